// Round 20
// baseline (120.383 us; speedup 1.0000x reference)
//
#include <hip/hip_runtime.h>
#include <math.h>

#define NQ   8192      // N queries per batch
#define NP   8192      // M points per batch
#define NF   128       // feature dim
#define NOUT 512       // output dim
#define NB   2         // batches
#define KNN  10
#define BNQ  (NB*NQ)   // 16384 total queries
#define QW   4         // queries per wave (r20: 2 -> 4, only change vs r19)
#define CAP  64        // candidate buffer slots per query
#define STILES 32      // pass-1 subset tiles (2048 points): tau_S >= true tau

typedef unsigned long long u64;
typedef unsigned int u32;
typedef unsigned short ushort_t;
typedef __attribute__((ext_vector_type(8))) short bf16x8;
typedef __attribute__((ext_vector_type(4))) float f32x4;

__device__ __forceinline__ u64 shfl64(u64 v, int src) {
  unsigned lo = (unsigned)__shfl((int)(unsigned)(v & 0xffffffffull), src, 64);
  unsigned hi = (unsigned)__shfl((int)(unsigned)(v >> 32), src, 64);
  return ((u64)hi << 32) | lo;
}
__device__ __forceinline__ u64 shflup64(u64 v) {
  unsigned lo = (unsigned)__shfl_up((int)(unsigned)(v & 0xffffffffull), 1, 64);
  unsigned hi = (unsigned)__shfl_up((int)(unsigned)(v >> 32), 1, 64);
  return ((u64)hi << 32) | lo;
}

// Shifted distance for SELECTION: d2' = p2 - 2 q.p  (3 fma). True d2 = d2'+q2.
__device__ __forceinline__ float dist2s(float m2x, float m2y, float m2z,
                                        float4 p) {
  return fmaf(m2x, p.x, fmaf(m2y, p.y, fmaf(m2z, p.z, p.w)));
}

// Monotone f32->u32 bit map: mono(a) < mono(b) (unsigned) <=> a < b (float).
__device__ __forceinline__ unsigned fmono(float f) {
  unsigned u = __float_as_uint(f);
  return u ^ ((unsigned)((int)u >> 31) | 0x80000000u);
}
// nextafter(f, +inf) for finite f incl. negatives and -0 (r7-verified).
__device__ __forceinline__ float nextupf(float f) {
  unsigned u = __float_as_uint(f);
  unsigned n = (u & 0x80000000u) ? ((u == 0x80000000u) ? 1u : u - 1u) : u + 1u;
  return __uint_as_float(n);
}

__device__ __forceinline__ float wmin64f(float v) {
#pragma unroll
  for (int off = 1; off < 64; off <<= 1)
    v = fminf(v, __shfl_xor(v, off, 64));
  return v;   // broadcast min across all 64 lanes (r5-verified)
}

// r8-verified order-independent distributed insert (full-exec only).
__device__ __forceinline__ void insert_loop(float d2, int idxv, int lane,
                                            u64& lst, float& dlv, float& th) {
  for (;;) {
    u64 mask = __ballot(d2 < th);
    if (!mask) break;
    int src = __builtin_ctzll(mask);
    float cd = __uint_as_float(
        (unsigned)__builtin_amdgcn_readlane(__float_as_int(d2), src));
    int  ci = __builtin_amdgcn_readlane(idxv, src);
    u64 kk = ((u64)fmono(cd) << 32) | (u32)ci;
    u64   prev  = shflup64(lst);
    float prevd = __shfl(dlv, lane - 1, 64);
    bool mylt = lst < kk;
    bool pins = (lane == 0) || (prev < kk);
    lst = mylt ? lst : (pins ? kk : prev);
    dlv = mylt ? dlv : (pins ? cd : prevd);
    float d9 = __uint_as_float(
        (unsigned)__builtin_amdgcn_readlane(__float_as_int(dlv), 9));
    th = fminf(th, nextupf(d9));
    if (lane == src) d2 = __builtin_nanf("");
  }
}

// round-to-nearest-even f32 -> bf16
__device__ __forceinline__ ushort_t f2bf(float x) {
  unsigned u = __float_as_uint(x);
  return (ushort_t)((u + 0x7FFFu + ((u >> 16) & 1u)) >> 16);
}

// ---------------------------------------------------------------------------
// Prep: pack points as (x,y,z,|p|^2); convert W[512][128] -> bf16 Wb[512][128]
// (r9/r10-verified)
// ---------------------------------------------------------------------------
__global__ __launch_bounds__(256) void prep_kernel(
    const float* __restrict__ gpcd, const float* __restrict__ W,
    float4* __restrict__ pts4, ushort_t* __restrict__ Wb)
{
  int tid = blockIdx.x * 256 + threadIdx.x;   // 0..65535
  if (tid < NB * NP) {
    const float* p = gpcd + (size_t)tid * 3;
    float x = p[0], y = p[1], z = p[2];
    float p2 = x * x + y * y + z * z;
    pts4[tid] = make_float4(x, y, z, p2);
  }
  Wb[tid] = f2bf(W[tid]);                     // 512*128 = 65536 elements
}

// ---------------------------------------------------------------------------
// Stage A+B (r19-verified structure; QW=4): subset pass-1 tau, compacting
// pass-2 (no loop-carried cross-lane deps), verified insert finalize.
// Each point tile load now serves 4 queries (load/loop overhead halves
// per query vs QW=2).
// ---------------------------------------------------------------------------
__global__ __launch_bounds__(256) void knn_interp_kernel(
    const float* __restrict__ geometry, const float4* __restrict__ pts4,
    const float* __restrict__ features, ushort_t* __restrict__ Abf)
{
  __shared__ float cdL[4][QW][CAP];
  __shared__ int   ciL[4][QW][CAP];

  const int lane = threadIdx.x & 63;
  const int wb   = threadIdx.x >> 6;    // wave within block
  const int wave = (blockIdx.x << 2) | wb;
  const int q0   = wave * QW;           // QW consecutive queries (same batch)
  const int b    = q0 >> 13;            // q0 / 8192
  const float4* __restrict__ P = pts4 + ((size_t)b << 13);

  float m2x[QW], m2y[QW], m2z[QW], q2[QW];
#pragma unroll
  for (int j = 0; j < QW; ++j) {
    const float* g = geometry + (size_t)(q0 + j) * 3;
    float x = g[0], y = g[1], z = g[2];
    q2[j]  = x * x + y * y + z * z;
    m2x[j] = -2.0f * x; m2y[j] = -2.0f * y; m2z[j] = -2.0f * z;
  }

  // ---- pass 1 (SUBSET): per-lane min of shifted d2' over 2048 points ----
  float lmin[QW];
#pragma unroll
  for (int j = 0; j < QW; ++j) lmin[j] = INFINITY;
#pragma unroll 2
  for (int t = 0; t < STILES; ++t) {
    const float4 p = P[(t << 6) | lane];
#pragma unroll
    for (int j = 0; j < QW; ++j)
      lmin[j] = fminf(lmin[j], dist2s(m2x[j], m2y[j], m2z[j], p));
  }

  // ---- tau_S = 10th-smallest lane-min of subset; th = nextup(tau_S) ----
  float th[QW];
#pragma unroll
  for (int j = 0; j < QW; ++j) {
    float lm  = lmin[j];
    float tau = 0.0f;
#pragma unroll
    for (int r = 0; r < KNN; ++r) {
      tau = wmin64f(lm);
      u64 mk = __ballot(lm == tau);
      int w = __builtin_ctzll(mk);
      if (lane == w) lm = INFINITY;
    }
    th[j] = nextupf(tau);               // admits ties at tau
  }

  u64   list[QW];
  float dl[QW];
  int   count[QW];
#pragma unroll
  for (int j = 0; j < QW; ++j) {
    list[j]  = 0xFFFFFFFFFFFFFFFFull;   // maximal key
    dl[j]    = INFINITY;
    count[j] = 0;
  }
  const float qnan = __builtin_nanf("");

  // finalize: run buffered candidates through the verified insert machinery.
  auto finalize = [&](int j) {
    for (int base2 = 0; base2 < count[j]; base2 += 64) {
      const int sidx = base2 + lane;
      float cd2 = qnan;
      int   cid = 0;
      if (sidx < count[j]) { cd2 = cdL[wb][j][sidx]; cid = ciL[wb][j][sidx]; }
      insert_loop(cd2, cid, lane, list[j], dl[j], th[j]);
    }
    count[j] = 0;
  };

  // ---- pass 2: streaming filter + compaction (no loop-carried deps) ----
  for (int t = 0; t < NP / 64; ++t) {
    const float4 p = P[(t << 6) | lane];
    const int  idx = (t << 6) | lane;
#pragma unroll
    for (int j = 0; j < QW; ++j) {
      const float d2 = dist2s(m2x[j], m2y[j], m2z[j], p);
      const bool hit = d2 < th[j];
      const u64 mask = __ballot(hit);
      if (!mask) continue;
      const int pc = __popcll(mask);               // wave-uniform
      if (count[j] + pc > CAP) {                   // overflow path
        finalize(j);                               // tightens th[j]
        float d2m = hit ? d2 : qnan;               // re-filter inside insert
        insert_loop(d2m, idx, lane, list[j], dl[j], th[j]);   // r10 inline
      } else {
        if (hit) {
          const int slot = count[j] +
              (int)__popcll(mask & ((1ull << lane) - 1ull));
          cdL[wb][j][slot] = d2;
          ciL[wb][j][slot] = idx;
        }
        count[j] += pc;
      }
    }
  }

  // ---- final selection from buffers ----
#pragma unroll
  for (int j = 0; j < QW; ++j) finalize(j);

  // ---- weights + feature interpolation; bf16 row-major output (r10) ----
  const float* __restrict__ F = features + (size_t)b * NP * NF;
#pragma unroll
  for (int j = 0; j < QW; ++j) {
    float td2 = fmaxf(dl[j] + q2[j], 0.0f);       // back to true d2, clamped
    float w   = 1.0f / (sqrtf(td2) + 1e-8f);      // meaningful on lanes 0..9
    float wsum = 0.0f;
#pragma unroll
    for (int jj = 0; jj < KNN; ++jj) wsum += __shfl(w, jj, 64);

    float a0 = 0.0f, a1 = 0.0f;
#pragma unroll
    for (int jj = 0; jj < KNN; ++jj) {
      float wj = __shfl(w, jj, 64) / wsum;
      int  mi  = (int)(u32)(shfl64(list[j], jj) & 0xffffffffull);
      const float2 f2 = *(const float2*)(F + (size_t)mi * NF + (lane << 1));
      a0 = fmaf(wj, f2.x, a0);
      a1 = fmaf(wj, f2.y, a1);
    }
    unsigned pack = (unsigned)f2bf(a0) | ((unsigned)f2bf(a1) << 16);
    *(unsigned*)(Abf + (size_t)(q0 + j) * NF + (lane << 1)) = pack;
  }
}

// ---------------------------------------------------------------------------
// Stage C (MFMA, r9/r10-verified): out[q][o] = sum_f A[q][f]*Wb[o][f]+bias[o]
// ---------------------------------------------------------------------------
__global__ __launch_bounds__(256) void proj_mfma(
    const ushort_t* __restrict__ Abf, const ushort_t* __restrict__ Wb,
    const float* __restrict__ bias, float* __restrict__ out)
{
  const int lane = threadIdx.x & 63;
  const int w    = threadIdx.x >> 6;        // wave 0..3
  const int mt   = blockIdx.x & 127;        // 128 m-blocks
  const int ot   = blockIdx.x >> 7;         // 8 o-blocks
  const int m0   = (mt << 7) + ((w & 1) << 6);   // wave's 64-row band
  const int o0   = (ot << 6) + ((w >> 1) << 5);  // wave's 32-col band
  const int r    = lane & 15;
  const int kg   = (lane >> 4) << 3;        // k offset 0,8,16,24

  f32x4 acc[4][2];
#pragma unroll
  for (int i = 0; i < 4; ++i)
#pragma unroll
    for (int jn = 0; jn < 2; ++jn) acc[i][jn] = (f32x4)0.0f;

#pragma unroll
  for (int ks = 0; ks < 4; ++ks) {
    const int k0 = (ks << 5) + kg;
    bf16x8 a[4], bb[2];
#pragma unroll
    for (int i = 0; i < 4; ++i)
      a[i] = *(const bf16x8*)(Abf + (size_t)(m0 + (i << 4) + r) * NF + k0);
#pragma unroll
    for (int jn = 0; jn < 2; ++jn)
      bb[jn] = *(const bf16x8*)(Wb + (size_t)(o0 + (jn << 4) + r) * NF + k0);
#pragma unroll
    for (int i = 0; i < 4; ++i)
#pragma unroll
      for (int jn = 0; jn < 2; ++jn)
        acc[i][jn] = __builtin_amdgcn_mfma_f32_16x16x32_bf16(
            a[i], bb[jn], acc[i][jn], 0, 0, 0);
  }

  const int crow = (lane >> 4) << 2;
#pragma unroll
  for (int jn = 0; jn < 2; ++jn) {
    const int oc = o0 + (jn << 4) + r;
    const float bv = bias[oc];
#pragma unroll
    for (int i = 0; i < 4; ++i) {
#pragma unroll
      for (int reg = 0; reg < 4; ++reg) {
        const int qm = m0 + (i << 4) + crow + reg;
        out[(size_t)qm * NOUT + oc] = acc[i][jn][reg] + bv;
      }
    }
  }
}

// ---------------------------------------------------------------------------
extern "C" void kernel_launch(void* const* d_in, const int* in_sizes, int n_in,
                              void* d_out, int out_size, void* d_ws, size_t ws_size,
                              hipStream_t stream) {
  const float* geometry = (const float*)d_in[0];   // [2,8192,3]
  const float* gpcd     = (const float*)d_in[1];   // [2,8192,3]
  const float* features = (const float*)d_in[2];   // [2,8192,128]
  const float* W        = (const float*)d_in[3];   // [512,128]
  const float* bias     = (const float*)d_in[4];   // [512]
  float* out = (float*)d_out;

  // workspace: Abf 4 MiB | pts4 256 KiB | Wb 128 KiB
  char*     ws   = (char*)d_ws;
  ushort_t* Abf  = (ushort_t*)ws;
  float4*   pts4 = (float4*)(ws + (size_t)BNQ * NF * 2);
  ushort_t* Wb   = (ushort_t*)(ws + (size_t)BNQ * NF * 2 + (size_t)NB * NP * 16);

  prep_kernel<<<256, 256, 0, stream>>>(gpcd, W, pts4, Wb);
  knn_interp_kernel<<<BNQ / (QW * 4), 256, 0, stream>>>(geometry, pts4, features, Abf);
  proj_mfma<<<(BNQ / 128) * (NOUT / 64), 256, 0, stream>>>(Abf, Wb, bias, out);
}

// Round 21
// 107.183 us; speedup vs baseline: 1.1232x; 1.1232x over previous
//
#include <hip/hip_runtime.h>
#include <math.h>

#define NQ   8192      // N queries per batch
#define NP   8192      // M points per batch
#define NF   128       // feature dim
#define NOUT 512       // output dim
#define NB   2         // batches
#define KNN  10
#define BNQ  (NB*NQ)   // 16384 total queries
#define QW   2         // queries per wave (r19-verified optimum)
#define CAP  64        // candidate buffer slots per query
#define STILES 32      // pass-1 subset tiles (2048 points): tau_S >= true tau

typedef unsigned long long u64;
typedef unsigned int u32;
typedef unsigned short ushort_t;
typedef __attribute__((ext_vector_type(8))) short bf16x8;
typedef __attribute__((ext_vector_type(4))) float f32x4;

__device__ __forceinline__ u64 shfl64(u64 v, int src) {
  unsigned lo = (unsigned)__shfl((int)(unsigned)(v & 0xffffffffull), src, 64);
  unsigned hi = (unsigned)__shfl((int)(unsigned)(v >> 32), src, 64);
  return ((u64)hi << 32) | lo;
}
__device__ __forceinline__ u64 shflup64(u64 v) {
  unsigned lo = (unsigned)__shfl_up((int)(unsigned)(v & 0xffffffffull), 1, 64);
  unsigned hi = (unsigned)__shfl_up((int)(unsigned)(v >> 32), 1, 64);
  return ((u64)hi << 32) | lo;
}

// Shifted distance for SELECTION: d2' = p2 - 2 q.p  (3 fma). True d2 = d2'+q2.
__device__ __forceinline__ float dist2s(float m2x, float m2y, float m2z,
                                        float4 p) {
  return fmaf(m2x, p.x, fmaf(m2y, p.y, fmaf(m2z, p.z, p.w)));
}

// Monotone f32->u32 bit map: mono(a) < mono(b) (unsigned) <=> a < b (float).
__device__ __forceinline__ unsigned fmono(float f) {
  unsigned u = __float_as_uint(f);
  return u ^ ((unsigned)((int)u >> 31) | 0x80000000u);
}
// nextafter(f, +inf) for finite f incl. negatives and -0 (r7-verified).
__device__ __forceinline__ float nextupf(float f) {
  unsigned u = __float_as_uint(f);
  unsigned n = (u & 0x80000000u) ? ((u == 0x80000000u) ? 1u : u - 1u) : u + 1u;
  return __uint_as_float(n);
}

__device__ __forceinline__ float wmin64f(float v) {
#pragma unroll
  for (int off = 1; off < 64; off <<= 1)
    v = fminf(v, __shfl_xor(v, off, 64));
  return v;   // broadcast min across all 64 lanes (r5-verified)
}

// r8-verified order-independent distributed insert (full-exec only).
__device__ __forceinline__ void insert_loop(float d2, int idxv, int lane,
                                            u64& lst, float& dlv, float& th) {
  for (;;) {
    u64 mask = __ballot(d2 < th);
    if (!mask) break;
    int src = __builtin_ctzll(mask);
    float cd = __uint_as_float(
        (unsigned)__builtin_amdgcn_readlane(__float_as_int(d2), src));
    int  ci = __builtin_amdgcn_readlane(idxv, src);
    u64 kk = ((u64)fmono(cd) << 32) | (u32)ci;
    u64   prev  = shflup64(lst);
    float prevd = __shfl(dlv, lane - 1, 64);
    bool mylt = lst < kk;
    bool pins = (lane == 0) || (prev < kk);
    lst = mylt ? lst : (pins ? kk : prev);
    dlv = mylt ? dlv : (pins ? cd : prevd);
    float d9 = __uint_as_float(
        (unsigned)__builtin_amdgcn_readlane(__float_as_int(dlv), 9));
    th = fminf(th, nextupf(d9));
    if (lane == src) d2 = __builtin_nanf("");
  }
}

// round-to-nearest-even f32 -> bf16
__device__ __forceinline__ ushort_t f2bf(float x) {
  unsigned u = __float_as_uint(x);
  return (ushort_t)((u + 0x7FFFu + ((u >> 16) & 1u)) >> 16);
}

// ---------------------------------------------------------------------------
// Prep: pack points as (x,y,z,|p|^2); convert W[512][128] -> bf16 Wb[512][128]
// (r9/r10-verified)
// ---------------------------------------------------------------------------
__global__ __launch_bounds__(256) void prep_kernel(
    const float* __restrict__ gpcd, const float* __restrict__ W,
    float4* __restrict__ pts4, ushort_t* __restrict__ Wb)
{
  int tid = blockIdx.x * 256 + threadIdx.x;   // 0..65535
  if (tid < NB * NP) {
    const float* p = gpcd + (size_t)tid * 3;
    float x = p[0], y = p[1], z = p[2];
    float p2 = x * x + y * y + z * z;
    pts4[tid] = make_float4(x, y, z, p2);
  }
  Wb[tid] = f2bf(W[tid]);                     // 512*128 = 65536 elements
}

// ---------------------------------------------------------------------------
// Stage A+B (r19-verified, 87.6us): subset pass-1 tau (2048 points; upper
// bound => exact filter), compacting pass-2 (ballot+popcount into LDS, no
// loop-carried cross-lane deps -> loads pipeline), verified insert finalize.
// Exact top-k incl. lax.top_k tie-breaks via u64 (mono(d2'),idx) keys.
// ---------------------------------------------------------------------------
__global__ __launch_bounds__(256) void knn_interp_kernel(
    const float* __restrict__ geometry, const float4* __restrict__ pts4,
    const float* __restrict__ features, ushort_t* __restrict__ Abf)
{
  __shared__ float cdL[4][QW][CAP];
  __shared__ int   ciL[4][QW][CAP];

  const int lane = threadIdx.x & 63;
  const int wb   = threadIdx.x >> 6;    // wave within block
  const int wave = (blockIdx.x << 2) | wb;
  const int q0   = wave * QW;           // QW consecutive queries (same batch)
  const int b    = q0 >> 13;            // q0 / 8192
  const float4* __restrict__ P = pts4 + ((size_t)b << 13);

  float m2x[QW], m2y[QW], m2z[QW], q2[QW];
#pragma unroll
  for (int j = 0; j < QW; ++j) {
    const float* g = geometry + (size_t)(q0 + j) * 3;
    float x = g[0], y = g[1], z = g[2];
    q2[j]  = x * x + y * y + z * z;
    m2x[j] = -2.0f * x; m2y[j] = -2.0f * y; m2z[j] = -2.0f * z;
  }

  // ---- pass 1 (SUBSET): per-lane min of shifted d2' over 2048 points ----
  float lmin[QW];
#pragma unroll
  for (int j = 0; j < QW; ++j) lmin[j] = INFINITY;
#pragma unroll 2
  for (int t = 0; t < STILES; ++t) {
    const float4 p = P[(t << 6) | lane];
#pragma unroll
    for (int j = 0; j < QW; ++j)
      lmin[j] = fminf(lmin[j], dist2s(m2x[j], m2y[j], m2z[j], p));
  }

  // ---- tau_S = 10th-smallest lane-min of subset; th = nextup(tau_S) ----
  float th[QW];
#pragma unroll
  for (int j = 0; j < QW; ++j) {
    float lm  = lmin[j];
    float tau = 0.0f;
#pragma unroll
    for (int r = 0; r < KNN; ++r) {
      tau = wmin64f(lm);
      u64 mk = __ballot(lm == tau);
      int w = __builtin_ctzll(mk);
      if (lane == w) lm = INFINITY;
    }
    th[j] = nextupf(tau);               // admits ties at tau
  }

  u64   list[QW];
  float dl[QW];
  int   count[QW];
#pragma unroll
  for (int j = 0; j < QW; ++j) {
    list[j]  = 0xFFFFFFFFFFFFFFFFull;   // maximal key
    dl[j]    = INFINITY;
    count[j] = 0;
  }
  const float qnan = __builtin_nanf("");

  // finalize: run buffered candidates through the verified insert machinery.
  auto finalize = [&](int j) {
    for (int base2 = 0; base2 < count[j]; base2 += 64) {
      const int sidx = base2 + lane;
      float cd2 = qnan;
      int   cid = 0;
      if (sidx < count[j]) { cd2 = cdL[wb][j][sidx]; cid = ciL[wb][j][sidx]; }
      insert_loop(cd2, cid, lane, list[j], dl[j], th[j]);
    }
    count[j] = 0;
  };

  // ---- pass 2: streaming filter + compaction (no loop-carried deps) ----
  for (int t = 0; t < NP / 64; ++t) {
    const float4 p = P[(t << 6) | lane];
    const int  idx = (t << 6) | lane;
#pragma unroll
    for (int j = 0; j < QW; ++j) {
      const float d2 = dist2s(m2x[j], m2y[j], m2z[j], p);
      const bool hit = d2 < th[j];
      const u64 mask = __ballot(hit);
      if (!mask) continue;
      const int pc = __popcll(mask);               // wave-uniform
      if (count[j] + pc > CAP) {                   // overflow path
        finalize(j);                               // tightens th[j]
        float d2m = hit ? d2 : qnan;               // re-filter inside insert
        insert_loop(d2m, idx, lane, list[j], dl[j], th[j]);   // r10 inline
      } else {
        if (hit) {
          const int slot = count[j] +
              (int)__popcll(mask & ((1ull << lane) - 1ull));
          cdL[wb][j][slot] = d2;
          ciL[wb][j][slot] = idx;
        }
        count[j] += pc;
      }
    }
  }

  // ---- final selection from buffers ----
#pragma unroll
  for (int j = 0; j < QW; ++j) finalize(j);

  // ---- weights + feature interpolation; bf16 row-major output (r10) ----
  const float* __restrict__ F = features + (size_t)b * NP * NF;
#pragma unroll
  for (int j = 0; j < QW; ++j) {
    float td2 = fmaxf(dl[j] + q2[j], 0.0f);       // back to true d2, clamped
    float w   = 1.0f / (sqrtf(td2) + 1e-8f);      // meaningful on lanes 0..9
    float wsum = 0.0f;
#pragma unroll
    for (int jj = 0; jj < KNN; ++jj) wsum += __shfl(w, jj, 64);

    float a0 = 0.0f, a1 = 0.0f;
#pragma unroll
    for (int jj = 0; jj < KNN; ++jj) {
      float wj = __shfl(w, jj, 64) / wsum;
      int  mi  = (int)(u32)(shfl64(list[j], jj) & 0xffffffffull);
      const float2 f2 = *(const float2*)(F + (size_t)mi * NF + (lane << 1));
      a0 = fmaf(wj, f2.x, a0);
      a1 = fmaf(wj, f2.y, a1);
    }
    unsigned pack = (unsigned)f2bf(a0) | ((unsigned)f2bf(a1) << 16);
    *(unsigned*)(Abf + (size_t)(q0 + j) * NF + (lane << 1)) = pack;
  }
}

// ---------------------------------------------------------------------------
// Stage C (MFMA, r9/r10-verified): out[q][o] = sum_f A[q][f]*Wb[o][f]+bias[o]
// ---------------------------------------------------------------------------
__global__ __launch_bounds__(256) void proj_mfma(
    const ushort_t* __restrict__ Abf, const ushort_t* __restrict__ Wb,
    const float* __restrict__ bias, float* __restrict__ out)
{
  const int lane = threadIdx.x & 63;
  const int w    = threadIdx.x >> 6;        // wave 0..3
  const int mt   = blockIdx.x & 127;        // 128 m-blocks
  const int ot   = blockIdx.x >> 7;         // 8 o-blocks
  const int m0   = (mt << 7) + ((w & 1) << 6);   // wave's 64-row band
  const int o0   = (ot << 6) + ((w >> 1) << 5);  // wave's 32-col band
  const int r    = lane & 15;
  const int kg   = (lane >> 4) << 3;        // k offset 0,8,16,24

  f32x4 acc[4][2];
#pragma unroll
  for (int i = 0; i < 4; ++i)
#pragma unroll
    for (int jn = 0; jn < 2; ++jn) acc[i][jn] = (f32x4)0.0f;

#pragma unroll
  for (int ks = 0; ks < 4; ++ks) {
    const int k0 = (ks << 5) + kg;
    bf16x8 a[4], bb[2];
#pragma unroll
    for (int i = 0; i < 4; ++i)
      a[i] = *(const bf16x8*)(Abf + (size_t)(m0 + (i << 4) + r) * NF + k0);
#pragma unroll
    for (int jn = 0; jn < 2; ++jn)
      bb[jn] = *(const bf16x8*)(Wb + (size_t)(o0 + (jn << 4) + r) * NF + k0);
#pragma unroll
    for (int i = 0; i < 4; ++i)
#pragma unroll
      for (int jn = 0; jn < 2; ++jn)
        acc[i][jn] = __builtin_amdgcn_mfma_f32_16x16x32_bf16(
            a[i], bb[jn], acc[i][jn], 0, 0, 0);
  }

  const int crow = (lane >> 4) << 2;
#pragma unroll
  for (int jn = 0; jn < 2; ++jn) {
    const int oc = o0 + (jn << 4) + r;
    const float bv = bias[oc];
#pragma unroll
    for (int i = 0; i < 4; ++i) {
#pragma unroll
      for (int reg = 0; reg < 4; ++reg) {
        const int qm = m0 + (i << 4) + crow + reg;
        out[(size_t)qm * NOUT + oc] = acc[i][jn][reg] + bv;
      }
    }
  }
}

// ---------------------------------------------------------------------------
extern "C" void kernel_launch(void* const* d_in, const int* in_sizes, int n_in,
                              void* d_out, int out_size, void* d_ws, size_t ws_size,
                              hipStream_t stream) {
  const float* geometry = (const float*)d_in[0];   // [2,8192,3]
  const float* gpcd     = (const float*)d_in[1];   // [2,8192,3]
  const float* features = (const float*)d_in[2];   // [2,8192,128]
  const float* W        = (const float*)d_in[3];   // [512,128]
  const float* bias     = (const float*)d_in[4];   // [512]
  float* out = (float*)d_out;

  // workspace: Abf 4 MiB | pts4 256 KiB | Wb 128 KiB
  char*     ws   = (char*)d_ws;
  ushort_t* Abf  = (ushort_t*)ws;
  float4*   pts4 = (float4*)(ws + (size_t)BNQ * NF * 2);
  ushort_t* Wb   = (ushort_t*)(ws + (size_t)BNQ * NF * 2 + (size_t)NB * NP * 16);

  prep_kernel<<<256, 256, 0, stream>>>(gpcd, W, pts4, Wb);
  knn_interp_kernel<<<BNQ / (QW * 4), 256, 0, stream>>>(geometry, pts4, features, Abf);
  proj_mfma<<<(BNQ / 128) * (NOUT / 64), 256, 0, stream>>>(Abf, Wb, bias, out);
}